// Round 10
// baseline (170.680 us; speedup 1.0000x reference)
//
#include <hip/hip_runtime.h>
#include <hip/hip_bf16.h>
#include <hip/hip_fp16.h>
#include <stdint.h>

#define B_   2
#define S_   4096
#define H_   512
#define NH_  8
#define HD_  64
#define M_   (B_*S_)          // 8192
// exp2-form constants: p = 2^( s*SC2 + min(j-i,0)*LOG2D - M2_i )
#define LOG2D (-0.15200309344504997f)  // log2(0.9)
#define SC2   (0.18033688011112042f)   // 0.125 * log2(e)
// fixed per-row max  M2_i = 17.312340 - i*LOG2D  (upper bound, see R2 notes)
// UNIVERSAL: arg = fma(min(j-i,0), LOG2D, fma(s,SC2, -M2_i)) valid everywhere.
// WINDOW: rows i>=256 attend only keys [0,256) (tail < ~2e-6 relative, see R6)
// R8: small blocks + oversubscription hide per-iter latency.
// R10: K/V dbuf at 40 KB / 4 blocks/CU -- prefetch after barrier works here.
// R11: XCD-swizzled GEMM blocks (per-XCD L2-resident A) + fp16 split partials.
// R12/R13 (REGRESSED, reverted): 3-kernel fusion + reg-staged GEMMs, 164-169us.
// R14: T5 setprio around attn MFMA: NEUTRAL (137.3). Kept.
// R15 (REGRESSED, reverted): GEMM K-tile dbuf: occupancy loss beat prefetch.
// R16: attn XCD-locality grid (1-D 1472, flat&7=xcd): ~neutral (136.4). Kept.
// R17 (REGRESSED, reverted): last-arriver combine via __threadfence: attn
//   93us -- device-scope fences x512 blocks serialize across non-coherent L2s.
// R18: gemm_out64 (64x128 tile, 512 blocks = 2/CU) replaces 1-block/CU
//   gemm_bt<1>: 136.4 -> 134.3. Kept.
// R19 (this round): fuse combine into gemm_out64 A-staging (the R1-proven
//   comb path -- absmax was bit-identical there; R1's slowness was its
//   1-block/CU structure, not comb). Tiles with (m0&4095)<256 (32/512
//   blocks) rebuild their A-chunk from pO/pl: same c-ascending fp32 sums +
//   bf16 rounding as combine_kernel -> bit-identical ab image in LDS.
//   5 -> 4 kernels; kills the combine junction (~11us model) w/o fences.

#define NFULL        4    // 64-row q-tiles 0..3 (rows < 256): full sweep, split-K
#define NCHUNK       8    // split-K: 8 chunks x 8 k-tiles (512 keys) each

typedef __attribute__((ext_vector_type(8))) short bf16x8_t;  // 8 bf16 (4 VGPRs)
typedef __attribute__((ext_vector_type(4))) float f32x4_t;
typedef __attribute__((ext_vector_type(8))) _Float16 f16x8_t;

// async global->LDS, 16B/lane; LDS dest = wave-uniform base + lane*16
__device__ __forceinline__ void gl_lds16(const __hip_bfloat16* g, __hip_bfloat16* l) {
  __builtin_amdgcn_global_load_lds(
      (__attribute__((address_space(1))) void*)(g),
      (__attribute__((address_space(3))) void*)(l),
      16, 0, 0);
}

// fused cast of the three fp32 inputs to bf16
__global__ __launch_bounds__(256)
void cast3_kernel(const float* __restrict__ x, const float* __restrict__ wq,
                  const float* __restrict__ wo,
                  __hip_bfloat16* __restrict__ xb, __hip_bfloat16* __restrict__ wqb,
                  __hip_bfloat16* __restrict__ wob) {
  const int N0 = M_ * H_;            // 4194304
  const int N1 = 3 * H_ * H_;        // 786432
  int i4 = (blockIdx.x * blockDim.x + threadIdx.x) * 4;
  const float* src; __hip_bfloat16* dst; int off;
  if (i4 < N0)           { src = x;  dst = xb;  off = i4; }
  else if (i4 < N0 + N1) { src = wq; dst = wqb; off = i4 - N0; }
  else                   { src = wo; dst = wob; off = i4 - N0 - N1; }
  float4 v = *(const float4*)(src + off);
  ushort4 o;
  __hip_bfloat16 h;
  h = __float2bfloat16(v.x); o.x = *(unsigned short*)&h;
  h = __float2bfloat16(v.y); o.y = *(unsigned short*)&h;
  h = __float2bfloat16(v.z); o.z = *(unsigned short*)&h;
  h = __float2bfloat16(v.w); o.w = *(unsigned short*)&h;
  *(ushort4*)((unsigned short*)dst + off) = o;
}

// C = A[M,K] * Bw[N,K]^T, 128x128 tile, BK=64, XOR-swizzled LDS, 8 barriers.
// XCD-aware block remap: flat%8 = XCD (round-robin heuristic, m09).
// EPI 0: scatter bf16 into q[bh][s][d], k[bh][s][d], vt[bh][d][s].
template<int EPI>
__global__ __launch_bounds__(256)
void gemm_bt(const __hip_bfloat16* __restrict__ A,
             const __hip_bfloat16* __restrict__ Bw,
             int K,
             __hip_bfloat16* __restrict__ qb,
             __hip_bfloat16* __restrict__ kb,
             __hip_bfloat16* __restrict__ vtb,
             float* __restrict__ outp,
             const float* __restrict__ bias) {
  __shared__ alignas(16) __hip_bfloat16 sA[128*64];   // 16 KB, row stride 64
  __shared__ alignas(16) __hip_bfloat16 sB[128*64];
  const int tid  = threadIdx.x;
  const int wave = tid >> 6, lane = tid & 63;
  const int quad = lane >> 4, l15 = lane & 15;
  const int wr = (wave >> 1) * 64, wc = (wave & 1) * 64;

  const int nbx  = gridDim.x;
  const int flat = blockIdx.y * nbx + blockIdx.x;
  const int xcd  = flat & 7, sq = flat >> 3;
  const int rows_per_xcd = gridDim.y >> 3;
  const int by = xcd * rows_per_xcd + sq / nbx;
  const int bx = sq % nbx;
  const int m0 = by * 128, n0 = bx * 128;

  const int sub  = lane >> 3;          // row within 8-row chunk-group
  const int plog = (lane & 7) ^ sub;   // => phys = logical ^ (row&7)

  f32x4_t acc[4][4] = {};

  for (int kt = 0; kt < K; kt += 64) {
    __syncthreads();
    #pragma unroll
    for (int cc = 0; cc < 4; cc++) {
      int c   = wave * 4 + cc;          // chunks 0..15, 1KB = 8 rows of 64 bf16
      int row = c * 8 + sub;
      gl_lds16(A  + (size_t)(m0 + row) * K + kt + plog * 8, sA + c * 512);
      gl_lds16(Bw + (size_t)(n0 + row) * K + kt + plog * 8, sB + c * 512);
    }
    __syncthreads();
    #pragma unroll
    for (int kh = 0; kh < 2; kh++) {
      bf16x8_t af[4], bfr[4];
      #pragma unroll
      for (int x = 0; x < 4; x++) {
        int row = wr + x * 16 + l15;
        int pos = kh * 4 + quad;
        af[x] = *(const bf16x8_t*)(sA + row * 64 + ((pos ^ (row & 7)) << 3));
      }
      #pragma unroll
      for (int y = 0; y < 4; y++) {
        int row = wc + y * 16 + l15;
        int pos = kh * 4 + quad;
        bfr[y] = *(const bf16x8_t*)(sB + row * 64 + ((pos ^ (row & 7)) << 3));
      }
      #pragma unroll
      for (int x = 0; x < 4; x++)
        #pragma unroll
        for (int y = 0; y < 4; y++)
          acc[x][y] = __builtin_amdgcn_mfma_f32_16x16x32_bf16(af[x], bfr[y], acc[x][y], 0, 0, 0);
    }
  }

  // epilogue: C/D layout col = lane&15, row = quad*4 + reg  (m89/m91-verified)
  if (EPI == 0 && (n0 >> 9) == 2) {
    #pragma unroll
    for (int x = 0; x < 4; x++) {
      int gr = m0 + wr + x * 16 + quad * 4;     // r=0 row; bb/sb uniform over r
      int bb = gr >> 12, sb = gr & 4095;
      #pragma unroll
      for (int y = 0; y < 4; y++) {
        int rem = (n0 - 1024) + wc + y * 16 + l15;   // in [0,512)
        int h = rem >> 6, d = rem & 63;
        ushort4 o; __hip_bfloat16 hv;
        hv = __float2bfloat16(acc[x][y][0]); o.x = *(unsigned short*)&hv;
        hv = __float2bfloat16(acc[x][y][1]); o.y = *(unsigned short*)&hv;
        hv = __float2bfloat16(acc[x][y][2]); o.z = *(unsigned short*)&hv;
        hv = __float2bfloat16(acc[x][y][3]); o.w = *(unsigned short*)&hv;
        *(ushort4*)(vtb + ((size_t)(bb * NH_ + h) * HD_ + d) * S_ + sb) = o;
      }
    }
  } else {
    #pragma unroll
    for (int x = 0; x < 4; x++) {
      #pragma unroll
      for (int y = 0; y < 4; y++) {
        #pragma unroll
        for (int r = 0; r < 4; r++) {
          int gr = m0 + wr + x*16 + quad*4 + r;
          int gc = n0 + wc + y*16 + l15;
          float v = acc[x][y][r];
          if (EPI == 0) {
            int bb = gr >> 12, s = gr & 4095;
            int t  = gc >> 9,  rem = gc & 511;
            int h  = rem >> 6, d = rem & 63;
            __hip_bfloat16 hv = __float2bfloat16(v);
            int bh = bb * NH_ + h;
            if (t == 0) qb[((size_t)bh * S_ + s) * HD_ + d] = hv;
            else        kb[((size_t)bh * S_ + s) * HD_ + d] = hv;
          } else {
            outp[(size_t)gr * H_ + gc] = v + bias[gc];
          }
        }
      }
    }
  }
}

// R18/R19: output projection, 64x128 tiles, 512 blocks (2/CU, 8 waves/CU).
// out = ab[8192,512] * wob[512,512]^T + bias. Same BK=64/kh MFMA order as
// gemm_bt -> bit-identical fp32. R19: tiles whose rows are all s<256
// rebuild their A-chunks from the split-K partials pO/pl (combine fused):
// per K-tile kt = head h, A[s][h*64+d] = (sum_c pO[bh,qt,c][s&63,d]) / L[s]
// with c-ascending fp32 sums + bf16 rounding == combine_kernel bit-exact.
__global__ __launch_bounds__(256)
void gemm_out64(const __hip_bfloat16* __restrict__ A,
                const __hip_bfloat16* __restrict__ Bw,
                const __half* __restrict__ pO,
                const float* __restrict__ pl,
                float* __restrict__ outp,
                const float* __restrict__ bias) {
  __shared__ alignas(16) __hip_bfloat16 sA[64*64];    // 8 KB
  __shared__ alignas(16) __hip_bfloat16 sB[128*64];   // 16 KB
  const int tid  = threadIdx.x;
  const int wave = tid >> 6, lane = tid & 63;
  const int quad = lane >> 4, l15 = lane & 15;
  const int wr = (wave >> 1) * 32, wc = (wave & 1) * 64;   // 2x2 waves over 32x64

  // XCD swizzle: 512 blocks; xcd owns 16 contiguous m-tiles (1MB A + 0.5MB B in L2)
  const int flat = blockIdx.x;
  const int xcd  = flat & 7, sq = flat >> 3;   // sq 0..63
  const int by = xcd * 16 + (sq >> 2);         // m-tile 0..127
  const int bx = sq & 3;                       // n-tile 0..3
  const int m0 = by * 64, n0 = bx * 128;
  const bool comb = (m0 & 4095) < 256;         // all 64 rows in split-K region

  const int sub  = lane >> 3;
  const int plog = (lane & 7) ^ sub;

  f32x4_t acc[2][4] = {};

  for (int kt = 0; kt < H_; kt += 64) {
    __syncthreads();
    #pragma unroll
    for (int cc = 0; cc < 6; cc++) {
      int cid = wave * 6 + cc;                 // 0..23, wave-uniform
      if (cid < 8) {
        int row = cid * 8 + sub;
        if (comb) {
          // rebuild A chunk from split-K partials (combine fused, R1-proven)
          const int s  = (m0 & 4095) + row;    // 0..255
          const int qt = s >> 6, rq = s & 63;
          const int h  = kt >> 6;
          const int bh = (m0 >> 12) * NH_ + h;
          const size_t base0 = ((size_t)bh * NFULL + qt) * NCHUNK;
          float L = 0.f;
          float o[8] = {};
          #pragma unroll
          for (int ch = 0; ch < NCHUNK; ch++) {
            L += pl[(base0 + ch) * 64 + rq];
            f16x8_t v = *(const f16x8_t*)(pO + (base0 + ch) * 4096 + rq * 64 + plog * 8);
            #pragma unroll
            for (int k = 0; k < 8; k++) o[k] += (float)v[k];
          }
          const float inv = 1.0f / L;
          bf16x8_t rr;
          #pragma unroll
          for (int k = 0; k < 8; k++) {
            __hip_bfloat16 hv = __float2bfloat16(o[k] * inv);
            rr[k] = *(short*)&hv;
          }
          *(bf16x8_t*)(sA + cid * 512 + lane * 8) = rr;
        } else {
          gl_lds16(A + (size_t)(m0 + row) * H_ + kt + plog * 8, sA + cid * 512);
        }
      } else {
        int row = (cid - 8) * 8 + sub;
        gl_lds16(Bw + (size_t)(n0 + row) * H_ + kt + plog * 8, sB + (cid - 8) * 512);
      }
    }
    __syncthreads();
    #pragma unroll
    for (int kh = 0; kh < 2; kh++) {
      bf16x8_t af[2], bfr[4];
      #pragma unroll
      for (int x = 0; x < 2; x++) {
        int row = wr + x * 16 + l15;
        int pos = kh * 4 + quad;
        af[x] = *(const bf16x8_t*)(sA + row * 64 + ((pos ^ (row & 7)) << 3));
      }
      #pragma unroll
      for (int y = 0; y < 4; y++) {
        int row = wc + y * 16 + l15;
        int pos = kh * 4 + quad;
        bfr[y] = *(const bf16x8_t*)(sB + row * 64 + ((pos ^ (row & 7)) << 3));
      }
      #pragma unroll
      for (int x = 0; x < 2; x++)
        #pragma unroll
        for (int y = 0; y < 4; y++)
          acc[x][y] = __builtin_amdgcn_mfma_f32_16x16x32_bf16(af[x], bfr[y], acc[x][y], 0, 0, 0);
    }
  }

  #pragma unroll
  for (int x = 0; x < 2; x++) {
    #pragma unroll
    for (int y = 0; y < 4; y++) {
      #pragma unroll
      for (int r = 0; r < 4; r++) {
        int gr = m0 + wr + x*16 + quad*4 + r;
        int gc = n0 + wc + y*16 + l15;
        outp[(size_t)gr * H_ + gc] = acc[x][y][r] + bias[gc];
      }
    }
  }
}

// stage one 64-key K tile + V^T tile into the given LDS buffers (async).
// waves 0-1 -> K (8 chunks), waves 2-3 -> V (8 chunks).
__device__ __forceinline__ void stage_kv(const __hip_bfloat16* __restrict__ kb,
                                         const __hip_bfloat16* __restrict__ vtb,
                                         int bh, int j0,
                                         __hip_bfloat16* dK, __hip_bfloat16* dV,
                                         int wave, int lane, int sub, int plog) {
  if (wave < 2) {
    #pragma unroll
    for (int cc = 0; cc < 4; cc++) {
      int c = wave * 4 + cc;                   // 0..7
      gl_lds16(kb + ((size_t)bh * S_ + j0 + c * 8 + sub) * HD_ + plog * 8, dK + c * 512);
    }
  } else {
    #pragma unroll
    for (int cc = 0; cc < 4; cc++) {
      int c = (wave - 2) * 4 + cc;             // 0..7 (d-rows)
      gl_lds16(vtb + ((size_t)bh * HD_ + c * 8 + sub) * S_ + j0 + plog * 8, dV + c * 512);
    }
  }
}

// Flash attention, recency bias, fixed analytic row-max, windowed keys.
// 64 q-rows x 64-key tiles, K/V double-buffered (40 KB LDS), one barrier/iter;
// prefetch after the barrier (R10-validated).
// R16: 1-D grid 1472, XCD-locality decode: flat&7 = xcd owns bh = xcd+8*b1.
// R14: s_setprio(1) around the QK and PV MFMA clusters (T5; neutral, kept).
__global__ __launch_bounds__(256)
void attn_kernel(const __hip_bfloat16* __restrict__ qb,
                 const __hip_bfloat16* __restrict__ kb,
                 const __hip_bfloat16* __restrict__ vtb,
                 __hip_bfloat16* __restrict__ ob,
                 __half* __restrict__ pO,
                 float* __restrict__ pl) {
  __shared__ alignas(16) __hip_bfloat16 sK[2][64*64];   // [kpos][d] 8-way swizzle
  __shared__ alignas(16) __hip_bfloat16 sV[2][64*64];   // [d][kpos] 8-way swizzle
  __shared__ alignas(16) __hip_bfloat16 sP[4][16*64];   // per-wave P, 8-way swizzle

  const int tid  = threadIdx.x;
  const int wave = tid >> 6, lane = tid & 63;
  const int quad = lane >> 4, l15 = lane & 15;

  // XCD-locality decode (T1): flat&7 = target XCD (m09 round-robin heuristic)
  const int flat = blockIdx.x;         // 0..1471
  const int xcd  = flat & 7;
  const int idx  = flat >> 3;          // 0..183
  const int b1   = idx / 92;           // 0..1
  const int w    = idx % 92;           // 0..91
  const int bh   = xcd + (b1 << 3);    // xcd owns bh = xcd and xcd+8

  int q0, jt0, niter, chunk = 0;
  bool direct;
  if (w < 60) { q0 = 256 + w * 64; jt0 = 0; niter = 4; direct = true; }
  else { int t = w - 60; chunk = t & 7; q0 = (t >> 3) * 64; jt0 = chunk * 8; niter = 8; direct = false; }

  // Q A-fragment for this wave's 16 rows (A[m=l15][k=quad*8+j])
  const __hip_bfloat16* qrow = qb + ((size_t)bh * S_ + q0 + wave * 16 + l15) * HD_;
  bf16x8_t aQ0 = *(const bf16x8_t*)(qrow + quad * 8);
  bf16x8_t aQ1 = *(const bf16x8_t*)(qrow + 32 + quad * 8);

  f32x4_t accO[4] = {};
  float l_r[4], negM2[4];
  const int row_i = q0 + wave * 16 + quad * 4;   // + r
  #pragma unroll
  for (int r = 0; r < 4; r++) {
    l_r[r] = 0.f;
    negM2[r] = -(17.312340f - LOG2D * (float)(row_i + r));
  }

  const int sub  = lane >> 3;
  const int plog = (lane & 7) ^ sub;             // phys = logical ^ (row&7)
  __hip_bfloat16* sPw = &sP[wave][0];

  // prologue: stage first tile into buffer 0
  stage_kv(kb, vtb, bh, jt0 * 64, &sK[0][0], &sV[0][0], wave, lane, sub, plog);

  for (int it = 0; it < niter; ++it) {
    const int cur = it & 1;
    // barrier: (a) all waves done reading buf[cur] (overwrite target of the
    // prefetch we're about to issue), (b) compiler's vmcnt(0) drains the loads
    // into buf[cur] issued last iteration -- a full compute phase ago.
    __syncthreads();
    if (it < niter - 1)
      stage_kv(kb, vtb, bh, (jt0 + it + 1) * 64,
               &sK[1 - cur][0], &sV[1 - cur][0], wave, lane, sub, plog);
    const __hip_bfloat16* cK = &sK[cur][0];
    const __hip_bfloat16* cV = &sV[cur][0];
    const int j0 = (jt0 + it) * 64;

    // S = Q K^T : 4 col-tiles of 16 keys
    f32x4_t sfr[4];
    __builtin_amdgcn_s_setprio(1);
    #pragma unroll
    for (int ni = 0; ni < 4; ni++) {
      int row = ni * 16 + l15;
      f32x4_t a = {};
      bf16x8_t b0 = *(const bf16x8_t*)(cK + row * 64 + ((quad       ^ (row & 7)) << 3));
      bf16x8_t b1v = *(const bf16x8_t*)(cK + row * 64 + (((quad + 4) ^ (row & 7)) << 3));
      a = __builtin_amdgcn_mfma_f32_16x16x32_bf16(aQ0, b0, a, 0, 0, 0);
      a = __builtin_amdgcn_mfma_f32_16x16x32_bf16(aQ1, b1v, a, 0, 0, 0);
      sfr[ni] = a;
    }
    __builtin_amdgcn_s_setprio(0);

    // softmax numerator, ONE universal formula:
    // arg = fma(min(j-i,0), LOG2D, fma(s, SC2, -M2_i))
    #pragma unroll
    for (int r = 0; r < 4; r++) {
      const float d0 = (float)(j0 + l15 - (row_i + r));
      const int row = quad * 4 + r;
      float psum = 0.f;
      #pragma unroll
      for (int ni = 0; ni < 4; ni++) {
        float dij = d0 + (float)(ni * 16);
        float arg = fmaf(fminf(dij, 0.f), LOG2D, fmaf(sfr[ni][r], SC2, negM2[r]));
        float p = __builtin_amdgcn_exp2f(arg);
        psum += p;
        int col = ni * 16 + l15;
        sPw[row * 64 + (((col >> 3) ^ (row & 7)) << 3) + (col & 7)] = __float2bfloat16(p);
      }
      l_r[r] += psum;
    }
    __builtin_amdgcn_sched_barrier(0);
    __builtin_amdgcn_s_waitcnt(0xC07F);   // lgkmcnt(0) only: sP visible, prefetch vmcnt stays in flight
    __builtin_amdgcn_sched_barrier(0);

    // O += P V : A-frags from sPw (rows l15), B-frags from cV (rows nd*16+l15)
    bf16x8_t aP0 = *(const bf16x8_t*)(sPw + l15 * 64 + ((quad       ^ (l15 & 7)) << 3));
    bf16x8_t aP1 = *(const bf16x8_t*)(sPw + l15 * 64 + (((quad + 4) ^ (l15 & 7)) << 3));
    __builtin_amdgcn_s_setprio(1);
    #pragma unroll
    for (int nd = 0; nd < 4; nd++) {
      int row = nd * 16 + l15;
      bf16x8_t b0 = *(const bf16x8_t*)(cV + row * 64 + ((quad       ^ (row & 7)) << 3));
      bf16x8_t b1v = *(const bf16x8_t*)(cV + row * 64 + (((quad + 4) ^ (row & 7)) << 3));
      accO[nd] = __builtin_amdgcn_mfma_f32_16x16x32_bf16(aP0, b0, accO[nd], 0, 0, 0);
      accO[nd] = __builtin_amdgcn_mfma_f32_16x16x32_bf16(aP1, b1v, accO[nd], 0, 0, 0);
    }
    __builtin_amdgcn_s_setprio(0);
    __builtin_amdgcn_sched_barrier(0);
  }

  // reduce l across the 16 lanes sharing each row
  #pragma unroll
  for (int r = 0; r < 4; r++) {
    float l = l_r[r];
    #pragma unroll
    for (int msk = 1; msk < 16; msk <<= 1) l += __shfl_xor(l, msk, 64);
    l_r[r] = l;
  }

  if (direct) {
    const int b = bh >> 3, h = bh & 7;
    #pragma unroll
    for (int r = 0; r < 4; r++) {
      float invr = 1.0f / l_r[r];
      #pragma unroll
      for (int nd = 0; nd < 4; nd++) {
        int srow = q0 + wave * 16 + quad * 4 + r;
        int col  = h * HD_ + nd * 16 + l15;
        ob[((size_t)b * S_ + srow) * H_ + col] = __float2bfloat16(accO[nd][r] * invr);
      }
    }
  } else {
    // partial: unnormalized O (fp16 -- bounded: p<=1 so |O| <= 512*max|v|)
    // + per-row l (shared fixed M => plain sums later)
    const int qt = q0 >> 6;                       // 0..3
    size_t base = ((size_t)bh * NFULL + qt) * NCHUNK + chunk;
    __half* po = pO + base * 4096;
    #pragma unroll
    for (int nd = 0; nd < 4; nd++)
      #pragma unroll
      for (int r = 0; r < 4; r++)
        po[(wave*16 + quad*4 + r) * 64 + nd*16 + l15] = __float2half(accO[nd][r]);
    if (l15 == 0) {
      #pragma unroll
      for (int r = 0; r < 4; r++)
        pl[base * 64 + wave*16 + quad*4 + r] = l_r[r];
    }
  }
}

extern "C" void kernel_launch(void* const* d_in, const int* in_sizes, int n_in,
                              void* d_out, int out_size, void* d_ws, size_t ws_size,
                              hipStream_t stream) {
  const float* x     = (const float*)d_in[0];
  const float* w_qkv = (const float*)d_in[1];
  const float* w_out = (const float*)d_in[2];
  const float* b_out = (const float*)d_in[3];
  float* out = (float*)d_out;

  char* ws = (char*)d_ws;
  __hip_bfloat16* xb  = (__hip_bfloat16*)(ws);                 // 8 MB (reused as attn out)
  __hip_bfloat16* wqb = (__hip_bfloat16*)(ws + (8u  << 20));   // 1.5 MB
  __hip_bfloat16* wob = (__hip_bfloat16*)(ws + (10u << 20));   // 0.5 MB
  __hip_bfloat16* qb  = (__hip_bfloat16*)(ws + (11u << 20));   // 8 MB
  __hip_bfloat16* kb  = (__hip_bfloat16*)(ws + (19u << 20));   // 8 MB
  __hip_bfloat16* vtb = (__hip_bfloat16*)(ws + (27u << 20));   // 8 MB
  __half*         pO  = (__half*)(ws + (36u << 20));           // 4 MB
  float*          pl  = (float*)(ws + (41u << 20));            // 0.13 MB
  __hip_bfloat16* ab  = xb;                                    // alias: xb dead after QKV GEMM

  cast3_kernel<<<dim3(5120), dim3(256), 0, stream>>>(x, w_qkv, w_out, xb, wqb, wob);
  gemm_bt<0><<<dim3(12, 64), dim3(256), 0, stream>>>(xb, wqb, H_, qb, kb, vtb, nullptr, nullptr);
  attn_kernel<<<dim3(1472), dim3(256), 0, stream>>>(qb, kb, vtb, ab, pO, pl);
  gemm_out64<<<dim3(512), dim3(256), 0, stream>>>(ab, wob, pO, pl, out, b_out);
}

// Round 11
// 139.637 us; speedup vs baseline: 1.2223x; 1.2223x over previous
//
#include <hip/hip_runtime.h>
#include <hip/hip_bf16.h>
#include <hip/hip_fp16.h>
#include <stdint.h>

#define B_   2
#define S_   4096
#define H_   512
#define NH_  8
#define HD_  64
#define M_   (B_*S_)          // 8192
// exp2-form constants: p = 2^( s*SC2 + min(j-i,0)*LOG2D - M2_i )
#define LOG2D (-0.15200309344504997f)  // log2(0.9)
#define SC2   (0.18033688011112042f)   // 0.125 * log2(e)
// fixed per-row max  M2_i = 17.312340 - i*LOG2D  (upper bound, see R2 notes)
// UNIVERSAL: arg = fma(min(j-i,0), LOG2D, fma(s,SC2, -M2_i)) valid everywhere.
// WINDOW: rows i>=256 attend only keys [0,256) (tail < ~2e-6 relative, see R6)
// R10: K/V dbuf at 40 KB / 4 blocks/CU -- prefetch after barrier works here.
// R11: XCD-swizzled GEMM blocks (per-XCD L2-resident A) + fp16 split partials.
// R12/R13 (REGRESSED, reverted): 3-kernel fusion + reg-staged GEMMs, 164-169us.
// R14: T5 setprio around attn MFMA: NEUTRAL. Kept.
// R15 (REGRESSED, reverted): GEMM K-tile dbuf: occupancy loss beat prefetch.
// R16: attn XCD-locality grid (1-D 1472, flat&7=xcd): ~neutral (136.4). Kept.
// R17 (REGRESSED, reverted): last-arriver combine via __threadfence (93us attn).
// R18: gemm_out64 (64x128 tile, 512 blocks = 2/CU) replaced 1-block/CU
//   gemm_bt<1>: 136.4 -> 134.3. Kept.
// R19 (REGRESSED, reverted): combine fused into gemm_out64 staging: 53us tail
//   (32 comb blocks x 512 KB cross-XCD reads, 4x redundant across n-tiles,
//   ~128 waves alive). Junction-removal 0-for-3; combine stays standalone.
// R20 (this round): QKV GEMM ported to the proven gemm_out64 skeleton:
//   64x128 tiles, grid 1536 = 6 blocks/CU FULLY co-resident (vs gemm_bt<0>'s
//   768 = 3/CU grid-limited, 8 latency-exposed K-steps). Same BK=64/kh MFMA
//   accumulation order per output element -> bit-identical q/k/vt. XCD
//   swizzle: xcd owns 16 m-tile band (1MB A + 1.5MB B, L2-resident).

#define NFULL        4    // 64-row q-tiles 0..3 (rows < 256): full sweep, split-K
#define NCHUNK       8    // split-K: 8 chunks x 8 k-tiles (512 keys) each

typedef __attribute__((ext_vector_type(8))) short bf16x8_t;  // 8 bf16 (4 VGPRs)
typedef __attribute__((ext_vector_type(4))) float f32x4_t;

// async global->LDS, 16B/lane; LDS dest = wave-uniform base + lane*16
__device__ __forceinline__ void gl_lds16(const __hip_bfloat16* g, __hip_bfloat16* l) {
  __builtin_amdgcn_global_load_lds(
      (__attribute__((address_space(1))) void*)(g),
      (__attribute__((address_space(3))) void*)(l),
      16, 0, 0);
}

// fused cast of the three fp32 inputs to bf16
__global__ __launch_bounds__(256)
void cast3_kernel(const float* __restrict__ x, const float* __restrict__ wq,
                  const float* __restrict__ wo,
                  __hip_bfloat16* __restrict__ xb, __hip_bfloat16* __restrict__ wqb,
                  __hip_bfloat16* __restrict__ wob) {
  const int N0 = M_ * H_;            // 4194304
  const int N1 = 3 * H_ * H_;        // 786432
  int i4 = (blockIdx.x * blockDim.x + threadIdx.x) * 4;
  const float* src; __hip_bfloat16* dst; int off;
  if (i4 < N0)           { src = x;  dst = xb;  off = i4; }
  else if (i4 < N0 + N1) { src = wq; dst = wqb; off = i4 - N0; }
  else                   { src = wo; dst = wob; off = i4 - N0 - N1; }
  float4 v = *(const float4*)(src + off);
  ushort4 o;
  __hip_bfloat16 h;
  h = __float2bfloat16(v.x); o.x = *(unsigned short*)&h;
  h = __float2bfloat16(v.y); o.y = *(unsigned short*)&h;
  h = __float2bfloat16(v.z); o.z = *(unsigned short*)&h;
  h = __float2bfloat16(v.w); o.w = *(unsigned short*)&h;
  *(ushort4*)((unsigned short*)dst + off) = o;
}

// R20: QKV projection on the gemm_out64 skeleton. C = xb[8192,512] *
// wqb[1536,512]^T, 64x128 tiles, BK=64, XOR-swizzled LDS, grid 1536 =
// 6 blocks/CU co-resident. Epilogue scatters q[bh][s][d], k[bh][s][d],
// vt[bh][d][s] (vt packed x4) -- same math order as gemm_bt -> bit-identical.
__global__ __launch_bounds__(256)
void gemm_qkv64(const __hip_bfloat16* __restrict__ A,
                const __hip_bfloat16* __restrict__ Bw,
                __hip_bfloat16* __restrict__ qb,
                __hip_bfloat16* __restrict__ kb,
                __hip_bfloat16* __restrict__ vtb) {
  __shared__ alignas(16) __hip_bfloat16 sA[64*64];    // 8 KB
  __shared__ alignas(16) __hip_bfloat16 sB[128*64];   // 16 KB
  const int tid  = threadIdx.x;
  const int wave = tid >> 6, lane = tid & 63;
  const int quad = lane >> 4, l15 = lane & 15;
  const int wr = (wave >> 1) * 32, wc = (wave & 1) * 64;   // 2x2 waves over 32x64

  // XCD swizzle: 1536 blocks; xcd owns m-tiles [xcd*16, +16) (1MB A-band)
  const int flat = blockIdx.x;
  const int xcd  = flat & 7, sq = flat >> 3;   // sq 0..191
  const int by = xcd * 16 + sq / 12;           // m-tile 0..127
  const int bx = sq % 12;                      // n-tile 0..11
  const int m0 = by * 64, n0 = bx * 128;

  const int sub  = lane >> 3;
  const int plog = (lane & 7) ^ sub;

  f32x4_t acc[2][4] = {};

  for (int kt = 0; kt < H_; kt += 64) {
    __syncthreads();
    #pragma unroll
    for (int cc = 0; cc < 6; cc++) {
      int cid = wave * 6 + cc;                 // 0..23, wave-uniform
      if (cid < 8) {
        int row = cid * 8 + sub;
        gl_lds16(A  + (size_t)(m0 + row) * H_ + kt + plog * 8, sA + cid * 512);
      } else {
        int row = (cid - 8) * 8 + sub;
        gl_lds16(Bw + (size_t)(n0 + row) * H_ + kt + plog * 8, sB + (cid - 8) * 512);
      }
    }
    __syncthreads();
    #pragma unroll
    for (int kh = 0; kh < 2; kh++) {
      bf16x8_t af[2], bfr[4];
      #pragma unroll
      for (int x = 0; x < 2; x++) {
        int row = wr + x * 16 + l15;
        int pos = kh * 4 + quad;
        af[x] = *(const bf16x8_t*)(sA + row * 64 + ((pos ^ (row & 7)) << 3));
      }
      #pragma unroll
      for (int y = 0; y < 4; y++) {
        int row = wc + y * 16 + l15;
        int pos = kh * 4 + quad;
        bfr[y] = *(const bf16x8_t*)(sB + row * 64 + ((pos ^ (row & 7)) << 3));
      }
      #pragma unroll
      for (int x = 0; x < 2; x++)
        #pragma unroll
        for (int y = 0; y < 4; y++)
          acc[x][y] = __builtin_amdgcn_mfma_f32_16x16x32_bf16(af[x], bfr[y], acc[x][y], 0, 0, 0);
    }
  }

  // epilogue: C/D layout col = lane&15, row = quad*4 + reg  (m89/m91-verified)
  if ((n0 >> 9) == 2) {
    // V^T block: pack the 4 consecutive s-positions into one 8B store
    #pragma unroll
    for (int x = 0; x < 2; x++) {
      int gr = m0 + wr + x * 16 + quad * 4;     // bb/sb uniform over r
      int bb = gr >> 12, sb = gr & 4095;
      #pragma unroll
      for (int y = 0; y < 4; y++) {
        int rem = (n0 - 1024) + wc + y * 16 + l15;   // in [0,512)
        int h = rem >> 6, d = rem & 63;
        ushort4 o; __hip_bfloat16 hv;
        hv = __float2bfloat16(acc[x][y][0]); o.x = *(unsigned short*)&hv;
        hv = __float2bfloat16(acc[x][y][1]); o.y = *(unsigned short*)&hv;
        hv = __float2bfloat16(acc[x][y][2]); o.z = *(unsigned short*)&hv;
        hv = __float2bfloat16(acc[x][y][3]); o.w = *(unsigned short*)&hv;
        *(ushort4*)(vtb + ((size_t)(bb * NH_ + h) * HD_ + d) * S_ + sb) = o;
      }
    }
  } else {
    #pragma unroll
    for (int x = 0; x < 2; x++) {
      #pragma unroll
      for (int y = 0; y < 4; y++) {
        #pragma unroll
        for (int r = 0; r < 4; r++) {
          int gr = m0 + wr + x*16 + quad*4 + r;
          int gc = n0 + wc + y*16 + l15;
          float v = acc[x][y][r];
          int bb = gr >> 12, s = gr & 4095;
          int t  = gc >> 9,  rem = gc & 511;
          int h  = rem >> 6, d = rem & 63;
          __hip_bfloat16 hv = __float2bfloat16(v);
          int bh = bb * NH_ + h;
          if (t == 0) qb[((size_t)bh * S_ + s) * HD_ + d] = hv;
          else        kb[((size_t)bh * S_ + s) * HD_ + d] = hv;
        }
      }
    }
  }
}

// R18: output projection, 64x128 tiles, 512 blocks (2/CU, 8 waves/CU).
// out = ab[8192,512] * wob[512,512]^T + bias. Same BK=64/kh MFMA order.
__global__ __launch_bounds__(256)
void gemm_out64(const __hip_bfloat16* __restrict__ A,
                const __hip_bfloat16* __restrict__ Bw,
                float* __restrict__ outp,
                const float* __restrict__ bias) {
  __shared__ alignas(16) __hip_bfloat16 sA[64*64];    // 8 KB
  __shared__ alignas(16) __hip_bfloat16 sB[128*64];   // 16 KB
  const int tid  = threadIdx.x;
  const int wave = tid >> 6, lane = tid & 63;
  const int quad = lane >> 4, l15 = lane & 15;
  const int wr = (wave >> 1) * 32, wc = (wave & 1) * 64;

  const int flat = blockIdx.x;
  const int xcd  = flat & 7, sq = flat >> 3;   // sq 0..63
  const int by = xcd * 16 + (sq >> 2);         // m-tile 0..127
  const int bx = sq & 3;                       // n-tile 0..3
  const int m0 = by * 64, n0 = bx * 128;

  const int sub  = lane >> 3;
  const int plog = (lane & 7) ^ sub;

  f32x4_t acc[2][4] = {};

  for (int kt = 0; kt < H_; kt += 64) {
    __syncthreads();
    #pragma unroll
    for (int cc = 0; cc < 6; cc++) {
      int cid = wave * 6 + cc;                 // 0..23, wave-uniform
      if (cid < 8) {
        int row = cid * 8 + sub;
        gl_lds16(A  + (size_t)(m0 + row) * H_ + kt + plog * 8, sA + cid * 512);
      } else {
        int row = (cid - 8) * 8 + sub;
        gl_lds16(Bw + (size_t)(n0 + row) * H_ + kt + plog * 8, sB + (cid - 8) * 512);
      }
    }
    __syncthreads();
    #pragma unroll
    for (int kh = 0; kh < 2; kh++) {
      bf16x8_t af[2], bfr[4];
      #pragma unroll
      for (int x = 0; x < 2; x++) {
        int row = wr + x * 16 + l15;
        int pos = kh * 4 + quad;
        af[x] = *(const bf16x8_t*)(sA + row * 64 + ((pos ^ (row & 7)) << 3));
      }
      #pragma unroll
      for (int y = 0; y < 4; y++) {
        int row = wc + y * 16 + l15;
        int pos = kh * 4 + quad;
        bfr[y] = *(const bf16x8_t*)(sB + row * 64 + ((pos ^ (row & 7)) << 3));
      }
      #pragma unroll
      for (int x = 0; x < 2; x++)
        #pragma unroll
        for (int y = 0; y < 4; y++)
          acc[x][y] = __builtin_amdgcn_mfma_f32_16x16x32_bf16(af[x], bfr[y], acc[x][y], 0, 0, 0);
    }
  }

  #pragma unroll
  for (int x = 0; x < 2; x++) {
    #pragma unroll
    for (int y = 0; y < 4; y++) {
      #pragma unroll
      for (int r = 0; r < 4; r++) {
        int gr = m0 + wr + x*16 + quad*4 + r;
        int gc = n0 + wc + y*16 + l15;
        outp[(size_t)gr * H_ + gc] = acc[x][y][r] + bias[gc];
      }
    }
  }
}

// stage one 64-key K tile + V^T tile into the given LDS buffers (async).
// waves 0-1 -> K (8 chunks), waves 2-3 -> V (8 chunks).
__device__ __forceinline__ void stage_kv(const __hip_bfloat16* __restrict__ kb,
                                         const __hip_bfloat16* __restrict__ vtb,
                                         int bh, int j0,
                                         __hip_bfloat16* dK, __hip_bfloat16* dV,
                                         int wave, int lane, int sub, int plog) {
  if (wave < 2) {
    #pragma unroll
    for (int cc = 0; cc < 4; cc++) {
      int c = wave * 4 + cc;                   // 0..7
      gl_lds16(kb + ((size_t)bh * S_ + j0 + c * 8 + sub) * HD_ + plog * 8, dK + c * 512);
    }
  } else {
    #pragma unroll
    for (int cc = 0; cc < 4; cc++) {
      int c = (wave - 2) * 4 + cc;             // 0..7 (d-rows)
      gl_lds16(vtb + ((size_t)bh * HD_ + c * 8 + sub) * S_ + j0 + plog * 8, dV + c * 512);
    }
  }
}

// Flash attention, recency bias, fixed analytic row-max, windowed keys.
// 64 q-rows x 64-key tiles, K/V double-buffered (40 KB LDS), one barrier/iter;
// prefetch after the barrier (R10-validated).
// R16: 1-D grid 1472, XCD-locality decode: flat&7 = xcd owns bh = xcd+8*b1.
// R14: s_setprio(1) around the QK and PV MFMA clusters (T5; neutral, kept).
__global__ __launch_bounds__(256)
void attn_kernel(const __hip_bfloat16* __restrict__ qb,
                 const __hip_bfloat16* __restrict__ kb,
                 const __hip_bfloat16* __restrict__ vtb,
                 __hip_bfloat16* __restrict__ ob,
                 __half* __restrict__ pO,
                 float* __restrict__ pl) {
  __shared__ alignas(16) __hip_bfloat16 sK[2][64*64];   // [kpos][d] 8-way swizzle
  __shared__ alignas(16) __hip_bfloat16 sV[2][64*64];   // [d][kpos] 8-way swizzle
  __shared__ alignas(16) __hip_bfloat16 sP[4][16*64];   // per-wave P, 8-way swizzle

  const int tid  = threadIdx.x;
  const int wave = tid >> 6, lane = tid & 63;
  const int quad = lane >> 4, l15 = lane & 15;

  // XCD-locality decode (T1): flat&7 = target XCD (m09 round-robin heuristic)
  const int flat = blockIdx.x;         // 0..1471
  const int xcd  = flat & 7;
  const int idx  = flat >> 3;          // 0..183
  const int b1   = idx / 92;           // 0..1
  const int w    = idx % 92;           // 0..91
  const int bh   = xcd + (b1 << 3);    // xcd owns bh = xcd and xcd+8

  int q0, jt0, niter, chunk = 0;
  bool direct;
  if (w < 60) { q0 = 256 + w * 64; jt0 = 0; niter = 4; direct = true; }
  else { int t = w - 60; chunk = t & 7; q0 = (t >> 3) * 64; jt0 = chunk * 8; niter = 8; direct = false; }

  // Q A-fragment for this wave's 16 rows (A[m=l15][k=quad*8+j])
  const __hip_bfloat16* qrow = qb + ((size_t)bh * S_ + q0 + wave * 16 + l15) * HD_;
  bf16x8_t aQ0 = *(const bf16x8_t*)(qrow + quad * 8);
  bf16x8_t aQ1 = *(const bf16x8_t*)(qrow + 32 + quad * 8);

  f32x4_t accO[4] = {};
  float l_r[4], negM2[4];
  const int row_i = q0 + wave * 16 + quad * 4;   // + r
  #pragma unroll
  for (int r = 0; r < 4; r++) {
    l_r[r] = 0.f;
    negM2[r] = -(17.312340f - LOG2D * (float)(row_i + r));
  }

  const int sub  = lane >> 3;
  const int plog = (lane & 7) ^ sub;             // phys = logical ^ (row&7)
  __hip_bfloat16* sPw = &sP[wave][0];

  // prologue: stage first tile into buffer 0
  stage_kv(kb, vtb, bh, jt0 * 64, &sK[0][0], &sV[0][0], wave, lane, sub, plog);

  for (int it = 0; it < niter; ++it) {
    const int cur = it & 1;
    // barrier: (a) all waves done reading buf[cur] (overwrite target of the
    // prefetch we're about to issue), (b) compiler's vmcnt(0) drains the loads
    // into buf[cur] issued last iteration -- a full compute phase ago.
    __syncthreads();
    if (it < niter - 1)
      stage_kv(kb, vtb, bh, (jt0 + it + 1) * 64,
               &sK[1 - cur][0], &sV[1 - cur][0], wave, lane, sub, plog);
    const __hip_bfloat16* cK = &sK[cur][0];
    const __hip_bfloat16* cV = &sV[cur][0];
    const int j0 = (jt0 + it) * 64;

    // S = Q K^T : 4 col-tiles of 16 keys
    f32x4_t sfr[4];
    __builtin_amdgcn_s_setprio(1);
    #pragma unroll
    for (int ni = 0; ni < 4; ni++) {
      int row = ni * 16 + l15;
      f32x4_t a = {};
      bf16x8_t b0 = *(const bf16x8_t*)(cK + row * 64 + ((quad       ^ (row & 7)) << 3));
      bf16x8_t b1v = *(const bf16x8_t*)(cK + row * 64 + (((quad + 4) ^ (row & 7)) << 3));
      a = __builtin_amdgcn_mfma_f32_16x16x32_bf16(aQ0, b0, a, 0, 0, 0);
      a = __builtin_amdgcn_mfma_f32_16x16x32_bf16(aQ1, b1v, a, 0, 0, 0);
      sfr[ni] = a;
    }
    __builtin_amdgcn_s_setprio(0);

    // softmax numerator, ONE universal formula:
    // arg = fma(min(j-i,0), LOG2D, fma(s, SC2, -M2_i))
    #pragma unroll
    for (int r = 0; r < 4; r++) {
      const float d0 = (float)(j0 + l15 - (row_i + r));
      const int row = quad * 4 + r;
      float psum = 0.f;
      #pragma unroll
      for (int ni = 0; ni < 4; ni++) {
        float dij = d0 + (float)(ni * 16);
        float arg = fmaf(fminf(dij, 0.f), LOG2D, fmaf(sfr[ni][r], SC2, negM2[r]));
        float p = __builtin_amdgcn_exp2f(arg);
        psum += p;
        int col = ni * 16 + l15;
        sPw[row * 64 + (((col >> 3) ^ (row & 7)) << 3) + (col & 7)] = __float2bfloat16(p);
      }
      l_r[r] += psum;
    }
    __builtin_amdgcn_sched_barrier(0);
    __builtin_amdgcn_s_waitcnt(0xC07F);   // lgkmcnt(0) only: sP visible, prefetch vmcnt stays in flight
    __builtin_amdgcn_sched_barrier(0);

    // O += P V : A-frags from sPw (rows l15), B-frags from cV (rows nd*16+l15)
    bf16x8_t aP0 = *(const bf16x8_t*)(sPw + l15 * 64 + ((quad       ^ (l15 & 7)) << 3));
    bf16x8_t aP1 = *(const bf16x8_t*)(sPw + l15 * 64 + (((quad + 4) ^ (l15 & 7)) << 3));
    __builtin_amdgcn_s_setprio(1);
    #pragma unroll
    for (int nd = 0; nd < 4; nd++) {
      int row = nd * 16 + l15;
      bf16x8_t b0 = *(const bf16x8_t*)(cV + row * 64 + ((quad       ^ (row & 7)) << 3));
      bf16x8_t b1v = *(const bf16x8_t*)(cV + row * 64 + (((quad + 4) ^ (row & 7)) << 3));
      accO[nd] = __builtin_amdgcn_mfma_f32_16x16x32_bf16(aP0, b0, accO[nd], 0, 0, 0);
      accO[nd] = __builtin_amdgcn_mfma_f32_16x16x32_bf16(aP1, b1v, accO[nd], 0, 0, 0);
    }
    __builtin_amdgcn_s_setprio(0);
    __builtin_amdgcn_sched_barrier(0);
  }

  // reduce l across the 16 lanes sharing each row
  #pragma unroll
  for (int r = 0; r < 4; r++) {
    float l = l_r[r];
    #pragma unroll
    for (int msk = 1; msk < 16; msk <<= 1) l += __shfl_xor(l, msk, 64);
    l_r[r] = l;
  }

  if (direct) {
    const int b = bh >> 3, h = bh & 7;
    #pragma unroll
    for (int r = 0; r < 4; r++) {
      float invr = 1.0f / l_r[r];
      #pragma unroll
      for (int nd = 0; nd < 4; nd++) {
        int srow = q0 + wave * 16 + quad * 4 + r;
        int col  = h * HD_ + nd * 16 + l15;
        ob[((size_t)b * S_ + srow) * H_ + col] = __float2bfloat16(accO[nd][r] * invr);
      }
    }
  } else {
    // partial: unnormalized O (fp16 -- bounded: p<=1 so |O| <= 512*max|v|)
    // + per-row l (shared fixed M => plain sums later)
    const int qt = q0 >> 6;                       // 0..3
    size_t base = ((size_t)bh * NFULL + qt) * NCHUNK + chunk;
    __half* po = pO + base * 4096;
    #pragma unroll
    for (int nd = 0; nd < 4; nd++)
      #pragma unroll
      for (int r = 0; r < 4; r++)
        po[(wave*16 + quad*4 + r) * 64 + nd*16 + l15] = __float2half(accO[nd][r]);
    if (l15 == 0) {
      #pragma unroll
      for (int r = 0; r < 4; r++)
        pl[base * 64 + wave*16 + quad*4 + r] = l_r[r];
    }
  }
}

// Merge NCHUNK fp16 partials (plain sums: shared fixed M). grid (NFULL,16), 256t.
__global__ __launch_bounds__(256)
void combine_kernel(const __half* __restrict__ pO,
                    const float* __restrict__ pl,
                    __hip_bfloat16* __restrict__ ob) {
  const int f  = blockIdx.x;
  const int bh = blockIdx.y;
  const int tid = threadIdx.x;
  const int rr = tid >> 2, cg = (tid & 3) * 16;
  const size_t base0 = ((size_t)bh * NFULL + f) * NCHUNK;

  float L = 0.f;
  #pragma unroll
  for (int c = 0; c < NCHUNK; c++) L += pl[(base0 + c) * 64 + rr];
  const float inv = 1.0f / L;

  float o[16];
  #pragma unroll
  for (int k = 0; k < 16; k++) o[k] = 0.f;
  #pragma unroll
  for (int c = 0; c < NCHUNK; c++) {
    const __half* src = pO + (base0 + c) * 4096 + rr * 64 + cg;
    #pragma unroll
    for (int k = 0; k < 16; k++) o[k] += __half2float(src[k]);
  }
  const int b = bh >> 3, h = bh & 7, s = f * 64 + rr;
  __hip_bfloat16* dst = ob + ((size_t)b * S_ + s) * H_ + h * HD_ + cg;
  #pragma unroll
  for (int k = 0; k < 16; k++) dst[k] = __float2bfloat16(o[k] * inv);
}

extern "C" void kernel_launch(void* const* d_in, const int* in_sizes, int n_in,
                              void* d_out, int out_size, void* d_ws, size_t ws_size,
                              hipStream_t stream) {
  const float* x     = (const float*)d_in[0];
  const float* w_qkv = (const float*)d_in[1];
  const float* w_out = (const float*)d_in[2];
  const float* b_out = (const float*)d_in[3];
  float* out = (float*)d_out;

  char* ws = (char*)d_ws;
  __hip_bfloat16* xb  = (__hip_bfloat16*)(ws);                 // 8 MB (reused as attn out)
  __hip_bfloat16* wqb = (__hip_bfloat16*)(ws + (8u  << 20));   // 1.5 MB
  __hip_bfloat16* wob = (__hip_bfloat16*)(ws + (10u << 20));   // 0.5 MB
  __hip_bfloat16* qb  = (__hip_bfloat16*)(ws + (11u << 20));   // 8 MB
  __hip_bfloat16* kb  = (__hip_bfloat16*)(ws + (19u << 20));   // 8 MB
  __hip_bfloat16* vtb = (__hip_bfloat16*)(ws + (27u << 20));   // 8 MB
  __half*         pO  = (__half*)(ws + (36u << 20));           // 4 MB
  float*          pl  = (float*)(ws + (41u << 20));            // 0.13 MB
  __hip_bfloat16* ab  = xb;                                    // alias: xb dead after QKV GEMM

  cast3_kernel<<<dim3(5120), dim3(256), 0, stream>>>(x, w_qkv, w_out, xb, wqb, wob);
  gemm_qkv64<<<dim3(1536), dim3(256), 0, stream>>>(xb, wqb, qb, kb, vtb);
  attn_kernel<<<dim3(1472), dim3(256), 0, stream>>>(qb, kb, vtb, ab, pO, pl);
  combine_kernel<<<dim3(NFULL, B_ * NH_), dim3(256), 0, stream>>>(pO, pl, ab);
  gemm_out64<<<dim3(512), dim3(256), 0, stream>>>(ab, wob, out, b_out);
}

// Round 12
// 131.550 us; speedup vs baseline: 1.2975x; 1.0615x over previous
//
#include <hip/hip_runtime.h>
#include <hip/hip_bf16.h>
#include <hip/hip_fp16.h>
#include <stdint.h>

#define B_   2
#define S_   4096
#define H_   512
#define NH_  8
#define HD_  64
#define M_   (B_*S_)          // 8192
// exp2-form constants: p = 2^( s*SC2 + min(j-i,0)*LOG2D - M2_i )
#define LOG2D (-0.15200309344504997f)  // log2(0.9)
#define SC2   (0.18033688011112042f)   // 0.125 * log2(e)
// fixed per-row max  M2_i = 17.312340 - i*LOG2D  (upper bound, see R2 notes)
// UNIVERSAL: arg = fma(min(j-i,0), LOG2D, fma(s,SC2, -M2_i)) valid everywhere.
// WINDOW: rows i>=256 attend only keys [0,256) (tail < ~2e-6 relative, see R6)
// R10: K/V dbuf at 40 KB / 4 blocks/CU -- prefetch after barrier works here.
// R11: XCD-swizzled GEMM blocks (per-XCD L2-resident A) + fp16 split partials.
// R12/R13 (REGRESSED, reverted): 3-kernel fusion + reg-staged GEMMs.
// R14: T5 setprio around attn MFMA: NEUTRAL. Kept.
// R15 (REGRESSED, reverted): GEMM K-tile dbuf: occupancy loss beat prefetch.
// R16: attn XCD-locality grid: ~neutral. Kept.
// R17 (REGRESSED, reverted): last-arriver combine via __threadfence.
// R18: gemm_out64 (64x128, 512 blocks = 2/CU) for output GEMM: 134.3. Kept.
// R19 (REGRESSED, reverted): combine fused into gemm_out64 (53us tail).
// R20 (REGRESSED, reverted): QKV on 64-tile skeleton: 139.6 -- 2x blocks =
//   2x staged B-panel traffic + 2x per-block overheads > occupancy gain.
//   QKV stays on gemm_bt 128^2.
// R21 (this round): attn TAIL FIX. Old grid 1472 > 1024 slots (40KB LDS ->
//   4 blocks/CU) -> second half-empty scheduling round + imbalanced blocks
//   (direct 4 iters vs splitK 8). New: direct blocks process TWO q-tiles
//   over the same staged K/V (2x compute/iter, staging amortized) -> 4x2
//   balanced vs splitK's 8x1; grid (30+32)x16 = 992 <= 1024 -> single
//   round, no tail. Per-row math sequence unchanged -> bit-identical.

#define NFULL        4    // 64-row q-tiles 0..3 (rows < 256): full sweep, split-K
#define NCHUNK       8    // split-K: 8 chunks x 8 k-tiles (512 keys) each

typedef __attribute__((ext_vector_type(8))) short bf16x8_t;  // 8 bf16 (4 VGPRs)
typedef __attribute__((ext_vector_type(4))) float f32x4_t;

// async global->LDS, 16B/lane; LDS dest = wave-uniform base + lane*16
__device__ __forceinline__ void gl_lds16(const __hip_bfloat16* g, __hip_bfloat16* l) {
  __builtin_amdgcn_global_load_lds(
      (__attribute__((address_space(1))) void*)(g),
      (__attribute__((address_space(3))) void*)(l),
      16, 0, 0);
}

// fused cast of the three fp32 inputs to bf16
__global__ __launch_bounds__(256)
void cast3_kernel(const float* __restrict__ x, const float* __restrict__ wq,
                  const float* __restrict__ wo,
                  __hip_bfloat16* __restrict__ xb, __hip_bfloat16* __restrict__ wqb,
                  __hip_bfloat16* __restrict__ wob) {
  const int N0 = M_ * H_;            // 4194304
  const int N1 = 3 * H_ * H_;        // 786432
  int i4 = (blockIdx.x * blockDim.x + threadIdx.x) * 4;
  const float* src; __hip_bfloat16* dst; int off;
  if (i4 < N0)           { src = x;  dst = xb;  off = i4; }
  else if (i4 < N0 + N1) { src = wq; dst = wqb; off = i4 - N0; }
  else                   { src = wo; dst = wob; off = i4 - N0 - N1; }
  float4 v = *(const float4*)(src + off);
  ushort4 o;
  __hip_bfloat16 h;
  h = __float2bfloat16(v.x); o.x = *(unsigned short*)&h;
  h = __float2bfloat16(v.y); o.y = *(unsigned short*)&h;
  h = __float2bfloat16(v.z); o.z = *(unsigned short*)&h;
  h = __float2bfloat16(v.w); o.w = *(unsigned short*)&h;
  *(ushort4*)((unsigned short*)dst + off) = o;
}

// C = A[M,K] * Bw[N,K]^T, 128x128 tile, BK=64, XOR-swizzled LDS, 8 barriers.
// XCD-aware block remap. EPI 0: scatter bf16 into q/k/vt.
template<int EPI>
__global__ __launch_bounds__(256)
void gemm_bt(const __hip_bfloat16* __restrict__ A,
             const __hip_bfloat16* __restrict__ Bw,
             int K,
             __hip_bfloat16* __restrict__ qb,
             __hip_bfloat16* __restrict__ kb,
             __hip_bfloat16* __restrict__ vtb,
             float* __restrict__ outp,
             const float* __restrict__ bias) {
  __shared__ alignas(16) __hip_bfloat16 sA[128*64];   // 16 KB, row stride 64
  __shared__ alignas(16) __hip_bfloat16 sB[128*64];
  const int tid  = threadIdx.x;
  const int wave = tid >> 6, lane = tid & 63;
  const int quad = lane >> 4, l15 = lane & 15;
  const int wr = (wave >> 1) * 64, wc = (wave & 1) * 64;

  const int nbx  = gridDim.x;
  const int flat = blockIdx.y * nbx + blockIdx.x;
  const int xcd  = flat & 7, sq = flat >> 3;
  const int rows_per_xcd = gridDim.y >> 3;
  const int by = xcd * rows_per_xcd + sq / nbx;
  const int bx = sq % nbx;
  const int m0 = by * 128, n0 = bx * 128;

  const int sub  = lane >> 3;          // row within 8-row chunk-group
  const int plog = (lane & 7) ^ sub;   // => phys = logical ^ (row&7)

  f32x4_t acc[4][4] = {};

  for (int kt = 0; kt < K; kt += 64) {
    __syncthreads();
    #pragma unroll
    for (int cc = 0; cc < 4; cc++) {
      int c   = wave * 4 + cc;          // chunks 0..15, 1KB = 8 rows of 64 bf16
      int row = c * 8 + sub;
      gl_lds16(A  + (size_t)(m0 + row) * K + kt + plog * 8, sA + c * 512);
      gl_lds16(Bw + (size_t)(n0 + row) * K + kt + plog * 8, sB + c * 512);
    }
    __syncthreads();
    #pragma unroll
    for (int kh = 0; kh < 2; kh++) {
      bf16x8_t af[4], bfr[4];
      #pragma unroll
      for (int x = 0; x < 4; x++) {
        int row = wr + x * 16 + l15;
        int pos = kh * 4 + quad;
        af[x] = *(const bf16x8_t*)(sA + row * 64 + ((pos ^ (row & 7)) << 3));
      }
      #pragma unroll
      for (int y = 0; y < 4; y++) {
        int row = wc + y * 16 + l15;
        int pos = kh * 4 + quad;
        bfr[y] = *(const bf16x8_t*)(sB + row * 64 + ((pos ^ (row & 7)) << 3));
      }
      #pragma unroll
      for (int x = 0; x < 4; x++)
        #pragma unroll
        for (int y = 0; y < 4; y++)
          acc[x][y] = __builtin_amdgcn_mfma_f32_16x16x32_bf16(af[x], bfr[y], acc[x][y], 0, 0, 0);
    }
  }

  // epilogue: C/D layout col = lane&15, row = quad*4 + reg  (m89/m91-verified)
  if (EPI == 0 && (n0 >> 9) == 2) {
    #pragma unroll
    for (int x = 0; x < 4; x++) {
      int gr = m0 + wr + x * 16 + quad * 4;     // bb/sb uniform over r
      int bb = gr >> 12, sb = gr & 4095;
      #pragma unroll
      for (int y = 0; y < 4; y++) {
        int rem = (n0 - 1024) + wc + y * 16 + l15;   // in [0,512)
        int h = rem >> 6, d = rem & 63;
        ushort4 o; __hip_bfloat16 hv;
        hv = __float2bfloat16(acc[x][y][0]); o.x = *(unsigned short*)&hv;
        hv = __float2bfloat16(acc[x][y][1]); o.y = *(unsigned short*)&hv;
        hv = __float2bfloat16(acc[x][y][2]); o.z = *(unsigned short*)&hv;
        hv = __float2bfloat16(acc[x][y][3]); o.w = *(unsigned short*)&hv;
        *(ushort4*)(vtb + ((size_t)(bb * NH_ + h) * HD_ + d) * S_ + sb) = o;
      }
    }
  } else {
    #pragma unroll
    for (int x = 0; x < 4; x++) {
      #pragma unroll
      for (int y = 0; y < 4; y++) {
        #pragma unroll
        for (int r = 0; r < 4; r++) {
          int gr = m0 + wr + x*16 + quad*4 + r;
          int gc = n0 + wc + y*16 + l15;
          float v = acc[x][y][r];
          if (EPI == 0) {
            int bb = gr >> 12, s = gr & 4095;
            int t  = gc >> 9,  rem = gc & 511;
            int h  = rem >> 6, d = rem & 63;
            __hip_bfloat16 hv = __float2bfloat16(v);
            int bh = bb * NH_ + h;
            if (t == 0) qb[((size_t)bh * S_ + s) * HD_ + d] = hv;
            else        kb[((size_t)bh * S_ + s) * HD_ + d] = hv;
          } else {
            outp[(size_t)gr * H_ + gc] = v + bias[gc];
          }
        }
      }
    }
  }
}

// R18: output projection, 64x128 tiles, 512 blocks (2/CU, 8 waves/CU).
__global__ __launch_bounds__(256)
void gemm_out64(const __hip_bfloat16* __restrict__ A,
                const __hip_bfloat16* __restrict__ Bw,
                float* __restrict__ outp,
                const float* __restrict__ bias) {
  __shared__ alignas(16) __hip_bfloat16 sA[64*64];    // 8 KB
  __shared__ alignas(16) __hip_bfloat16 sB[128*64];   // 16 KB
  const int tid  = threadIdx.x;
  const int wave = tid >> 6, lane = tid & 63;
  const int quad = lane >> 4, l15 = lane & 15;
  const int wr = (wave >> 1) * 32, wc = (wave & 1) * 64;

  const int flat = blockIdx.x;
  const int xcd  = flat & 7, sq = flat >> 3;   // sq 0..63
  const int by = xcd * 16 + (sq >> 2);         // m-tile 0..127
  const int bx = sq & 3;                       // n-tile 0..3
  const int m0 = by * 64, n0 = bx * 128;

  const int sub  = lane >> 3;
  const int plog = (lane & 7) ^ sub;

  f32x4_t acc[2][4] = {};

  for (int kt = 0; kt < H_; kt += 64) {
    __syncthreads();
    #pragma unroll
    for (int cc = 0; cc < 6; cc++) {
      int cid = wave * 6 + cc;                 // 0..23, wave-uniform
      if (cid < 8) {
        int row = cid * 8 + sub;
        gl_lds16(A  + (size_t)(m0 + row) * H_ + kt + plog * 8, sA + cid * 512);
      } else {
        int row = (cid - 8) * 8 + sub;
        gl_lds16(Bw + (size_t)(n0 + row) * H_ + kt + plog * 8, sB + (cid - 8) * 512);
      }
    }
    __syncthreads();
    #pragma unroll
    for (int kh = 0; kh < 2; kh++) {
      bf16x8_t af[2], bfr[4];
      #pragma unroll
      for (int x = 0; x < 2; x++) {
        int row = wr + x * 16 + l15;
        int pos = kh * 4 + quad;
        af[x] = *(const bf16x8_t*)(sA + row * 64 + ((pos ^ (row & 7)) << 3));
      }
      #pragma unroll
      for (int y = 0; y < 4; y++) {
        int row = wc + y * 16 + l15;
        int pos = kh * 4 + quad;
        bfr[y] = *(const bf16x8_t*)(sB + row * 64 + ((pos ^ (row & 7)) << 3));
      }
      #pragma unroll
      for (int x = 0; x < 2; x++)
        #pragma unroll
        for (int y = 0; y < 4; y++)
          acc[x][y] = __builtin_amdgcn_mfma_f32_16x16x32_bf16(af[x], bfr[y], acc[x][y], 0, 0, 0);
    }
  }

  #pragma unroll
  for (int x = 0; x < 2; x++) {
    #pragma unroll
    for (int y = 0; y < 4; y++) {
      #pragma unroll
      for (int r = 0; r < 4; r++) {
        int gr = m0 + wr + x*16 + quad*4 + r;
        int gc = n0 + wc + y*16 + l15;
        outp[(size_t)gr * H_ + gc] = acc[x][y][r] + bias[gc];
      }
    }
  }
}

// stage one 64-key K tile + V^T tile into the given LDS buffers (async).
// waves 0-1 -> K (8 chunks), waves 2-3 -> V (8 chunks).
__device__ __forceinline__ void stage_kv(const __hip_bfloat16* __restrict__ kb,
                                         const __hip_bfloat16* __restrict__ vtb,
                                         int bh, int j0,
                                         __hip_bfloat16* dK, __hip_bfloat16* dV,
                                         int wave, int lane, int sub, int plog) {
  if (wave < 2) {
    #pragma unroll
    for (int cc = 0; cc < 4; cc++) {
      int c = wave * 4 + cc;                   // 0..7
      gl_lds16(kb + ((size_t)bh * S_ + j0 + c * 8 + sub) * HD_ + plog * 8, dK + c * 512);
    }
  } else {
    #pragma unroll
    for (int cc = 0; cc < 4; cc++) {
      int c = (wave - 2) * 4 + cc;             // 0..7 (d-rows)
      gl_lds16(vtb + ((size_t)bh * HD_ + c * 8 + sub) * S_ + j0 + plog * 8, dV + c * 512);
    }
  }
}

// Flash attention, recency bias, fixed analytic row-max, windowed keys.
// R21: grid 992 (4/CU x 248 CUs, single scheduling round). Per bh, 62 slots:
//   w<30  -> DOUBLE direct block: q-tiles rows [256+128w, +128), keys
//            [0,256), 4 iters x 2 q-groups (K/V staging amortized 2x).
//   w>=30 -> t=w-30: split-K q-tile t>>3 (rows<256), chunk t&7, 8 iters.
// Balanced: 4x2 == 8x1 compute per block. XCD decode: flat&7 = xcd owns
// bh = xcd + 8*(idx/62). K/V dbuf 40KB, prefetch-after-barrier (R10).
// Per-row math sequence identical to R18 -> bit-identical output.
__global__ __launch_bounds__(256)
void attn_kernel(const __hip_bfloat16* __restrict__ qb,
                 const __hip_bfloat16* __restrict__ kb,
                 const __hip_bfloat16* __restrict__ vtb,
                 __hip_bfloat16* __restrict__ ob,
                 __half* __restrict__ pO,
                 float* __restrict__ pl) {
  __shared__ alignas(16) __hip_bfloat16 sK[2][64*64];   // [kpos][d] 8-way swizzle
  __shared__ alignas(16) __hip_bfloat16 sV[2][64*64];   // [d][kpos] 8-way swizzle
  __shared__ alignas(16) __hip_bfloat16 sP[4][16*64];   // per-wave P, 8-way swizzle

  const int tid  = threadIdx.x;
  const int wave = tid >> 6, lane = tid & 63;
  const int quad = lane >> 4, l15 = lane & 15;

  // XCD-locality decode: flat&7 = target XCD (m09 round-robin heuristic)
  const int flat = blockIdx.x;         // 0..991
  const int xcd  = flat & 7;
  const int idx  = flat >> 3;          // 0..123
  const int b1   = idx / 62;           // 0..1
  const int w    = idx % 62;           // 0..61
  const int bh   = xcd + (b1 << 3);    // xcd owns bh = xcd and xcd+8

  int q0, jt0, niter, chunk = 0, NQ;
  bool direct;
  if (w < 30) { q0 = 256 + w * 128; jt0 = 0; niter = 4; direct = true;  NQ = 2; }
  else { int t = w - 30; chunk = t & 7; q0 = (t >> 3) * 64; jt0 = chunk * 8;
         niter = 8; direct = false; NQ = 1; }

  // Q A-fragments: qi-th group covers rows q0 + qi*64 + wave*16 + l15
  bf16x8_t aQ0[2], aQ1[2];
  #pragma unroll
  for (int qi = 0; qi < 2; qi++) {
    if (qi < NQ) {
      const __hip_bfloat16* qrow =
          qb + ((size_t)bh * S_ + q0 + qi * 64 + wave * 16 + l15) * HD_;
      aQ0[qi] = *(const bf16x8_t*)(qrow + quad * 8);
      aQ1[qi] = *(const bf16x8_t*)(qrow + 32 + quad * 8);
    }
  }

  f32x4_t accO[2][4] = {};
  float l_r[2][4], negM2[2][4];
  const int row_i = q0 + wave * 16 + quad * 4;   // + qi*64 + r
  #pragma unroll
  for (int qi = 0; qi < 2; qi++)
    #pragma unroll
    for (int r = 0; r < 4; r++) {
      l_r[qi][r] = 0.f;
      negM2[qi][r] = -(17.312340f - LOG2D * (float)(row_i + qi * 64 + r));
    }

  const int sub  = lane >> 3;
  const int plog = (lane & 7) ^ sub;             // phys = logical ^ (row&7)
  __hip_bfloat16* sPw = &sP[wave][0];

  // prologue: stage first tile into buffer 0
  stage_kv(kb, vtb, bh, jt0 * 64, &sK[0][0], &sV[0][0], wave, lane, sub, plog);

  for (int it = 0; it < niter; ++it) {
    const int cur = it & 1;
    // barrier: (a) all waves done reading buf[cur], (b) implicit vmcnt(0)
    // drains loads issued one full compute phase ago.
    __syncthreads();
    if (it < niter - 1)
      stage_kv(kb, vtb, bh, (jt0 + it + 1) * 64,
               &sK[1 - cur][0], &sV[1 - cur][0], wave, lane, sub, plog);
    const __hip_bfloat16* cK = &sK[cur][0];
    const __hip_bfloat16* cV = &sV[cur][0];
    const int j0 = (jt0 + it) * 64;

    #pragma unroll
    for (int qi = 0; qi < 2; qi++) {
      if (qi >= NQ) break;   // block-uniform; qi static via unroll

      // S = Q K^T : 4 col-tiles of 16 keys
      f32x4_t sfr[4];
      __builtin_amdgcn_s_setprio(1);
      #pragma unroll
      for (int ni = 0; ni < 4; ni++) {
        int row = ni * 16 + l15;
        f32x4_t a = {};
        bf16x8_t b0 = *(const bf16x8_t*)(cK + row * 64 + ((quad       ^ (row & 7)) << 3));
        bf16x8_t b1v = *(const bf16x8_t*)(cK + row * 64 + (((quad + 4) ^ (row & 7)) << 3));
        a = __builtin_amdgcn_mfma_f32_16x16x32_bf16(aQ0[qi], b0, a, 0, 0, 0);
        a = __builtin_amdgcn_mfma_f32_16x16x32_bf16(aQ1[qi], b1v, a, 0, 0, 0);
        sfr[ni] = a;
      }
      __builtin_amdgcn_s_setprio(0);

      // softmax numerator: arg = fma(min(j-i,0), LOG2D, fma(s, SC2, -M2_i))
      #pragma unroll
      for (int r = 0; r < 4; r++) {
        const float d0 = (float)(j0 + l15 - (row_i + qi * 64 + r));
        const int row = quad * 4 + r;
        float psum = 0.f;
        #pragma unroll
        for (int ni = 0; ni < 4; ni++) {
          float dij = d0 + (float)(ni * 16);
          float arg = fmaf(fminf(dij, 0.f), LOG2D, fmaf(sfr[ni][r], SC2, negM2[qi][r]));
          float p = __builtin_amdgcn_exp2f(arg);
          psum += p;
          int col = ni * 16 + l15;
          sPw[row * 64 + (((col >> 3) ^ (row & 7)) << 3) + (col & 7)] = __float2bfloat16(p);
        }
        l_r[qi][r] += psum;
      }
      __builtin_amdgcn_sched_barrier(0);
      __builtin_amdgcn_s_waitcnt(0xC07F);   // lgkmcnt(0): sP visible; vmcnt in flight
      __builtin_amdgcn_sched_barrier(0);

      // O += P V
      bf16x8_t aP0 = *(const bf16x8_t*)(sPw + l15 * 64 + ((quad       ^ (l15 & 7)) << 3));
      bf16x8_t aP1 = *(const bf16x8_t*)(sPw + l15 * 64 + (((quad + 4) ^ (l15 & 7)) << 3));
      __builtin_amdgcn_s_setprio(1);
      #pragma unroll
      for (int nd = 0; nd < 4; nd++) {
        int row = nd * 16 + l15;
        bf16x8_t b0 = *(const bf16x8_t*)(cV + row * 64 + ((quad       ^ (row & 7)) << 3));
        bf16x8_t b1v = *(const bf16x8_t*)(cV + row * 64 + (((quad + 4) ^ (row & 7)) << 3));
        accO[qi][nd] = __builtin_amdgcn_mfma_f32_16x16x32_bf16(aP0, b0, accO[qi][nd], 0, 0, 0);
        accO[qi][nd] = __builtin_amdgcn_mfma_f32_16x16x32_bf16(aP1, b1v, accO[qi][nd], 0, 0, 0);
      }
      __builtin_amdgcn_s_setprio(0);
      __builtin_amdgcn_sched_barrier(0);
    }
  }

  // reduce l across the 16 lanes sharing each row
  #pragma unroll
  for (int qi = 0; qi < 2; qi++) {
    if (qi >= NQ) break;
    #pragma unroll
    for (int r = 0; r < 4; r++) {
      float l = l_r[qi][r];
      #pragma unroll
      for (int msk = 1; msk < 16; msk <<= 1) l += __shfl_xor(l, msk, 64);
      l_r[qi][r] = l;
    }
  }

  if (direct) {
    const int b = bh >> 3, h = bh & 7;
    #pragma unroll
    for (int qi = 0; qi < 2; qi++) {
      #pragma unroll
      for (int r = 0; r < 4; r++) {
        float invr = 1.0f / l_r[qi][r];
        #pragma unroll
        for (int nd = 0; nd < 4; nd++) {
          int srow = q0 + qi * 64 + wave * 16 + quad * 4 + r;
          int col  = h * HD_ + nd * 16 + l15;
          ob[((size_t)b * S_ + srow) * H_ + col] = __float2bfloat16(accO[qi][nd][r] * invr);
        }
      }
    }
  } else {
    // partial: unnormalized O (fp16) + per-row l (shared fixed M)
    const int qt = q0 >> 6;                       // 0..3
    size_t base = ((size_t)bh * NFULL + qt) * NCHUNK + chunk;
    __half* po = pO + base * 4096;
    #pragma unroll
    for (int nd = 0; nd < 4; nd++)
      #pragma unroll
      for (int r = 0; r < 4; r++)
        po[(wave*16 + quad*4 + r) * 64 + nd*16 + l15] = __float2half(accO[0][nd][r]);
    if (l15 == 0) {
      #pragma unroll
      for (int r = 0; r < 4; r++)
        pl[base * 64 + wave*16 + quad*4 + r] = l_r[0][r];
    }
  }
}

// Merge NCHUNK fp16 partials (plain sums: shared fixed M). grid (NFULL,16), 256t.
__global__ __launch_bounds__(256)
void combine_kernel(const __half* __restrict__ pO,
                    const float* __restrict__ pl,
                    __hip_bfloat16* __restrict__ ob) {
  const int f  = blockIdx.x;
  const int bh = blockIdx.y;
  const int tid = threadIdx.x;
  const int rr = tid >> 2, cg = (tid & 3) * 16;
  const size_t base0 = ((size_t)bh * NFULL + f) * NCHUNK;

  float L = 0.f;
  #pragma unroll
  for (int c = 0; c < NCHUNK; c++) L += pl[(base0 + c) * 64 + rr];
  const float inv = 1.0f / L;

  float o[16];
  #pragma unroll
  for (int k = 0; k < 16; k++) o[k] = 0.f;
  #pragma unroll
  for (int c = 0; c < NCHUNK; c++) {
    const __half* src = pO + (base0 + c) * 4096 + rr * 64 + cg;
    #pragma unroll
    for (int k = 0; k < 16; k++) o[k] += __half2float(src[k]);
  }
  const int b = bh >> 3, h = bh & 7, s = f * 64 + rr;
  __hip_bfloat16* dst = ob + ((size_t)b * S_ + s) * H_ + h * HD_ + cg;
  #pragma unroll
  for (int k = 0; k < 16; k++) dst[k] = __float2bfloat16(o[k] * inv);
}

extern "C" void kernel_launch(void* const* d_in, const int* in_sizes, int n_in,
                              void* d_out, int out_size, void* d_ws, size_t ws_size,
                              hipStream_t stream) {
  const float* x     = (const float*)d_in[0];
  const float* w_qkv = (const float*)d_in[1];
  const float* w_out = (const float*)d_in[2];
  const float* b_out = (const float*)d_in[3];
  float* out = (float*)d_out;

  char* ws = (char*)d_ws;
  __hip_bfloat16* xb  = (__hip_bfloat16*)(ws);                 // 8 MB (reused as attn out)
  __hip_bfloat16* wqb = (__hip_bfloat16*)(ws + (8u  << 20));   // 1.5 MB
  __hip_bfloat16* wob = (__hip_bfloat16*)(ws + (10u << 20));   // 0.5 MB
  __hip_bfloat16* qb  = (__hip_bfloat16*)(ws + (11u << 20));   // 8 MB
  __hip_bfloat16* kb  = (__hip_bfloat16*)(ws + (19u << 20));   // 8 MB
  __hip_bfloat16* vtb = (__hip_bfloat16*)(ws + (27u << 20));   // 8 MB
  __half*         pO  = (__half*)(ws + (36u << 20));           // 4 MB
  float*          pl  = (float*)(ws + (41u << 20));            // 0.13 MB
  __hip_bfloat16* ab  = xb;                                    // alias: xb dead after QKV GEMM

  cast3_kernel<<<dim3(5120), dim3(256), 0, stream>>>(x, w_qkv, w_out, xb, wqb, wob);
  gemm_bt<0><<<dim3(12, 64), dim3(256), 0, stream>>>(xb, wqb, H_, qb, kb, vtb, nullptr, nullptr);
  attn_kernel<<<dim3(992), dim3(256), 0, stream>>>(qb, kb, vtb, ab, pO, pl);
  combine_kernel<<<dim3(NFULL, B_ * NH_), dim3(256), 0, stream>>>(pO, pl, ab);
  gemm_out64<<<dim3(512), dim3(256), 0, stream>>>(ab, wob, out, b_out);
}